// Round 4
// baseline (372.103 us; speedup 1.0000x reference)
//
#include <hip/hip_runtime.h>

// Sizes are fixed by the problem.
#define S_HID 2048
#define S_SEQ 2048
#define S_B   2
#define S_NH  16
#define S_HD  128
#define S_M   (S_B * S_SEQ)   // 4096 rows
#define S_BH  (S_B * S_NH)    // 32

typedef __bf16 bf16_t;
typedef __bf16 bf16x8 __attribute__((ext_vector_type(8)));
typedef __bf16 bf16x4 __attribute__((ext_vector_type(4)));
typedef float  floatx4 __attribute__((ext_vector_type(4)));
typedef float  floatx16 __attribute__((ext_vector_type(16)));

typedef __attribute__((address_space(1))) unsigned int as1_uint;
typedef __attribute__((address_space(3))) unsigned int as3_uint;

// async global->LDS, 16B per lane; LDS dest = wave-uniform base + lane*16
__device__ __forceinline__ void gload_lds16(const void* g, void* l) {
    __builtin_amdgcn_global_load_lds((as1_uint*)g, (as3_uint*)l, 16, 0, 0);
}

// ---------------- fp32 -> bf16 convert: X + all 4 weights in one launch ----------------
__global__ void cvt_all(const float* __restrict__ x,
                        const float* __restrict__ qw, const float* __restrict__ kw,
                        const float* __restrict__ vw, const float* __restrict__ ow,
                        bf16_t* __restrict__ Xb, bf16_t* __restrict__ Wqkv) {
    const int XV = (S_M * S_HID) >> 2;      // 2^21 vec4
    const int WV = (S_HID * S_HID) >> 2;    // 2^20 vec4 per weight
    const int total = XV + 4 * WV;
    int stride = gridDim.x * blockDim.x;
    for (int i = blockIdx.x * blockDim.x + threadIdx.x; i < total; i += stride) {
        const float* src;
        bf16x4* dst;
        int local;
        if (i < XV) {
            src = x; local = i; dst = (bf16x4*)Xb;
        } else {
            int j = i - XV;
            int r = j >> 20;
            local = j & (WV - 1);
            src = r == 0 ? qw : r == 1 ? kw : r == 2 ? vw : ow;
            dst = (bf16x4*)Wqkv + (size_t)r * WV;
        }
        float4 v = ((const float4*)src)[local];
        bf16x4 o;
        o.x = (bf16_t)v.x; o.y = (bf16_t)v.y; o.z = (bf16_t)v.z; o.w = (bf16_t)v.w;
        dst[local] = o;
    }
}

// ---------------- fused QKV GEMM ----------------
// A[4096x2048] bf16, Wqkv stacked [6144x2048] bf16. Grid (48, 32).
// 128x128 tile, single-buffered 2-barrier structure. PINNED: this is the
// measured optimum for this dispatch (103.5 µs, ~990 TF, MfmaUtil 44%).
// Two deep-pipeline rewrites (R1 256^2 8-phase: 137 µs; R3 128x256
// triple-buffer counted-vmcnt: 121 µs) both regressed — at 1 block/CU the
// counted-vmcnt schedule loses more TLP than it gains pipeline depth.
// Do not re-attempt without a structurally different geometry.
__global__ __launch_bounds__(256, 4)
void gemm_qkv(const bf16_t* __restrict__ A, const bf16_t* __restrict__ W,
              const float* __restrict__ qbias, const float* __restrict__ kbias,
              const float* __restrict__ vbias,
              bf16_t* __restrict__ Qo, bf16_t* __restrict__ Ko, bf16_t* __restrict__ Vto,
              float qscale) {
    __shared__ __align__(16) bf16_t ldsA[128 * 64];
    __shared__ __align__(16) bf16_t ldsB[128 * 64];
    const int tid = threadIdx.x;
    const int wid = tid >> 6, lane = tid & 63;
    const int m0 = blockIdx.y * 128, n0 = blockIdx.x * 128;
    const int wm = (wid & 1) * 64, wn = (wid >> 1) * 64;
    const int lm = lane & 15, quad = lane >> 4;
    const int srow = lane >> 3;
    const int scol = lane & 7;

    floatx4 acc[4][4];
    #pragma unroll
    for (int i = 0; i < 4; ++i)
        #pragma unroll
        for (int j = 0; j < 4; ++j)
            acc[i][j] = (floatx4){0.f, 0.f, 0.f, 0.f};

    for (int kt = 0; kt < S_HID; kt += 64) {
        #pragma unroll
        for (int i = 0; i < 4; ++i) {
            int slot = i * 4 + wid;
            int row = slot * 8 + srow;
            int cg = scol ^ (row & 7);
            gload_lds16(A + (size_t)(m0 + row) * S_HID + kt + cg * 8, &ldsA[slot * 512]);
            gload_lds16(W + (size_t)(n0 + row) * S_HID + kt + cg * 8, &ldsB[slot * 512]);
        }
        __syncthreads();
        #pragma unroll
        for (int k2 = 0; k2 < 2; ++k2) {
            bf16x8 af[4], bfr[4];
            #pragma unroll
            for (int i = 0; i < 4; ++i) {
                int row = wm + i * 16 + lm;
                int cc = (k2 * 4 + quad) ^ (row & 7);
                af[i] = *(const bf16x8*)&ldsA[row * 64 + cc * 8];
            }
            #pragma unroll
            for (int j = 0; j < 4; ++j) {
                int row = wn + j * 16 + lm;
                int cc = (k2 * 4 + quad) ^ (row & 7);
                bfr[j] = *(const bf16x8*)&ldsB[row * 64 + cc * 8];
            }
            #pragma unroll
            for (int i = 0; i < 4; ++i)
                #pragma unroll
                for (int j = 0; j < 4; ++j)
                    acc[i][j] = __builtin_amdgcn_mfma_f32_16x16x32_bf16(af[i], bfr[j], acc[i][j], 0, 0, 0);
        }
        __syncthreads();
    }

    const int region = n0 >> 11;   // 0=Q, 1=K, 2=V (wave-uniform)
    if (region < 2) {
        bf16_t* Ob = region ? Ko : Qo;
        const float* bias = region ? kbias : qbias;
        float scale = region ? 1.0f : qscale;
        #pragma unroll
        for (int i = 0; i < 4; ++i) {
            #pragma unroll
            for (int j = 0; j < 4; ++j) {
                int n = n0 + wn + j * 16 + lm;
                float bv = bias[n & 2047];
                int nl = n & 2047;
                int h = nl >> 7, d = nl & 127;
                #pragma unroll
                for (int r = 0; r < 4; ++r) {
                    int m = m0 + wm + i * 16 + quad * 4 + r;
                    int b = m >> 11, s = m & 2047;
                    Ob[(((size_t)(b * S_NH + h)) * S_SEQ + s) * S_HD + d] =
                        (bf16_t)((acc[i][j][r] + bv) * scale);
                }
            }
        }
    } else {
        // V^T: out[((b*16+h)*128 + d) * 2048 + s], 4 consecutive s per store
        #pragma unroll
        for (int i = 0; i < 4; ++i) {
            #pragma unroll
            for (int j = 0; j < 4; ++j) {
                int n = n0 + wn + j * 16 + lm;
                int nl = n & 2047;
                float bv = vbias[nl];
                int h = nl >> 7, d = nl & 127;
                int m = m0 + wm + i * 16 + quad * 4;
                int b = m >> 11, s = m & 2047;
                bf16x4 ov;
                #pragma unroll
                for (int r = 0; r < 4; ++r) ov[r] = (bf16_t)(acc[i][j][r] + bv);
                *(bf16x4*)&Vto[(((size_t)(b * S_NH + h)) * S_HD + d) * S_SEQ + s] = ov;
            }
        }
    }
}

// ---------------- output GEMM: out = A[4096x2048] * W[2048x2048]^T + bias (fp32) ----------------
__global__ __launch_bounds__(256, 3)
void gemm_out(const bf16_t* __restrict__ A, const bf16_t* __restrict__ W,
              const float* __restrict__ bias, float* __restrict__ out) {
    __shared__ __align__(16) bf16_t ldsA[128 * 64];
    __shared__ __align__(16) bf16_t ldsB[128 * 64];
    const int tid = threadIdx.x;
    const int wid = tid >> 6, lane = tid & 63;
    const int m0 = blockIdx.y * 128, n0 = blockIdx.x * 128;
    const int wm = (wid & 1) * 64, wn = (wid >> 1) * 64;
    const int lm = lane & 15, quad = lane >> 4;
    const int srow = lane >> 3;
    const int scol = lane & 7;

    floatx4 acc[4][4];
    #pragma unroll
    for (int i = 0; i < 4; ++i)
        #pragma unroll
        for (int j = 0; j < 4; ++j)
            acc[i][j] = (floatx4){0.f, 0.f, 0.f, 0.f};

    for (int kt = 0; kt < S_HID; kt += 64) {
        #pragma unroll
        for (int i = 0; i < 4; ++i) {
            int slot = i * 4 + wid;
            int row = slot * 8 + srow;
            int cg = scol ^ (row & 7);
            gload_lds16(A + (size_t)(m0 + row) * S_HID + kt + cg * 8, &ldsA[slot * 512]);
            gload_lds16(W + (size_t)(n0 + row) * S_HID + kt + cg * 8, &ldsB[slot * 512]);
        }
        __syncthreads();
        #pragma unroll
        for (int k2 = 0; k2 < 2; ++k2) {
            bf16x8 af[4], bfr[4];
            #pragma unroll
            for (int i = 0; i < 4; ++i) {
                int row = wm + i * 16 + lm;
                int cc = (k2 * 4 + quad) ^ (row & 7);
                af[i] = *(const bf16x8*)&ldsA[row * 64 + cc * 8];
            }
            #pragma unroll
            for (int j = 0; j < 4; ++j) {
                int row = wn + j * 16 + lm;
                int cc = (k2 * 4 + quad) ^ (row & 7);
                bfr[j] = *(const bf16x8*)&ldsB[row * 64 + cc * 8];
            }
            #pragma unroll
            for (int i = 0; i < 4; ++i)
                #pragma unroll
                for (int j = 0; j < 4; ++j)
                    acc[i][j] = __builtin_amdgcn_mfma_f32_16x16x32_bf16(af[i], bfr[j], acc[i][j], 0, 0, 0);
        }
        __syncthreads();
    }

    #pragma unroll
    for (int i = 0; i < 4; ++i) {
        #pragma unroll
        for (int j = 0; j < 4; ++j) {
            int n = n0 + wn + j * 16 + lm;
            float bv = bias[n];
            #pragma unroll
            for (int r = 0; r < 4; ++r) {
                int m = m0 + wm + i * 16 + quad * 4 + r;
                out[(size_t)m * S_HID + n] = acc[i][j][r] + bv;
            }
        }
    }
}

// Build PV B-fragment (16 keys) from packed P values via cross-half exchange.
__device__ __forceinline__ bf16x8 make_pfrag(bf16x4 lo, bf16x4 hi, int h) {
    int2 li = __builtin_bit_cast(int2, lo);
    int2 hh = __builtin_bit_cast(int2, hi);
    int2 xl, xh;
    xl.x = __shfl_xor(li.x, 32); xl.y = __shfl_xor(li.y, 32);
    xh.x = __shfl_xor(hh.x, 32); xh.y = __shfl_xor(hh.y, 32);
    int2 flo, fhi;
    flo.x = h ? xh.x : li.x;  flo.y = h ? xh.y : li.y;
    fhi.x = h ? hh.x : xl.x;  fhi.y = h ? hh.y : xl.y;
    bf16x4 a = __builtin_bit_cast(bf16x4, flo);
    bf16x4 b = __builtin_bit_cast(bf16x4, fhi);
    return __builtin_shufflevector(a, b, 0, 1, 2, 3, 4, 5, 6, 7);
}

// ---------------- flash attention (causal), S^T orientation, 64-key tiles ----------------
// Q,K: [bh][s][d] bf16 (Q pre-scaled by 1/sqrt(d)*log2e); Vt: [bh][d][s] bf16
// O: [b][s][h*128+d] bf16.
// Grid 512: bh = bx&31 (same-bh blocks share XCD), idx = bx>>5;
// qt = idx<8 ? idx : 23-idx  -> blocks bx and bx+256 (likely co-resident on a
// CU) have complementary work (36 half-tiles total). 64-key K/V tiles,
// double-buffered: LDS = 64KB -> 2 blocks/CU, 2 waves/SIMD co-scheduling.
// T5: setprio(1) around the MFMA clusters (phase-diverse waves regime,
// measured ~-5 µs). T13: defer-max (measured ~-7 µs) — skip the O-rescale
// pass when __all(mx - m_st <= 8); P then bounded by 2^8 (bf16-safe; first
// tile always rescales since m_st = -1e30 forces the branch).
// NOTE: with 64-key tiles under a 128-q block the causal diagonal spans the
// LAST TWO key-tiles -> mask applies for kti >= nkt-2 (was the R5 bug).
__global__ __launch_bounds__(256, 2)
void attn(const bf16_t* __restrict__ Q, const bf16_t* __restrict__ K,
          const bf16_t* __restrict__ Vt, bf16_t* __restrict__ O) {
    __shared__ __align__(16) bf16_t ldsK[2][64 * 128];    // 2 x 16KB
    __shared__ __align__(16) bf16_t ldsV[2][128 * 64];    // 2 x 16KB
    const int tid = threadIdx.x, wid = tid >> 6, lane = tid & 63;
    const int lm = lane & 15, quad = lane >> 4;           // K staging roles
    const int srow = lane >> 3, scol = lane & 7;          // V staging roles
    const int c31 = lane & 31, h = lane >> 5, r7 = lane & 7;  // compute roles
    const int bx = blockIdx.x;
    const int bh = bx & 31, idx = bx >> 5;
    const int qt = idx < 8 ? idx : 23 - idx;
    const int q0 = qt * 128;
    const int b = bh >> 4, hd = bh & 15;

    const bf16_t* Kbase = K + (size_t)bh * S_SEQ * S_HD;
    const bf16_t* Vbase = Vt + (size_t)bh * S_HD * S_SEQ;

    const int qcol = q0 + wid * 32 + c31;      // this lane's q (= S^T column)
    const int nkt = qt * 2 + 2;                // 64-key tiles

    // Q fragments (B-operand): B[k = ks*16 + h*8 + j][n = c31]
    bf16x8 qf[8];
    {
        const bf16_t* qp = Q + ((size_t)bh * S_SEQ + qcol) * S_HD + h * 8;
        #pragma unroll
        for (int ks = 0; ks < 8; ++ks) qf[ks] = *(const bf16x8*)(qp + ks * 16);
    }

    floatx16 oa[4];
    #pragma unroll
    for (int jd = 0; jd < 4; ++jd)
        #pragma unroll
        for (int e = 0; e < 16; ++e) oa[jd][e] = 0.f;
    float m_st = -1e30f, l_st = 0.f;

    // stage tile 0 into buf 0
    #pragma unroll
    for (int i = 0; i < 4; ++i) {
        int slot = i * 4 + wid;                 // 0..15
        int krow = slot * 4 + quad;             // 0..63 (K: 4 rows x 256B per KB)
        int kcg = lm ^ (krow & 7);
        gload_lds16(Kbase + (size_t)krow * S_HD + kcg * 8, &ldsK[0][slot * 512]);
        int vrow = slot * 8 + srow;             // 0..127 (V: 8 rows x 128B per KB)
        int vcg = scol ^ (vrow & 7);
        gload_lds16(Vbase + (size_t)vrow * S_SEQ + vcg * 8, &ldsV[0][slot * 512]);
    }

    int pp = 0;
    for (int kti = 0; kti < nkt; ++kti) {
        const int kt = kti * 64;
        __syncthreads();   // drains staging of tile kti

        if (kti + 1 < nkt) {   // prefetch tile kti+1 into the other buffer
            const int ktn = kt + 64;
            #pragma unroll
            for (int i = 0; i < 4; ++i) {
                int slot = i * 4 + wid;
                int krow = slot * 4 + quad;
                int kcg = lm ^ (krow & 7);
                gload_lds16(Kbase + (size_t)(ktn + krow) * S_HD + kcg * 8, &ldsK[pp ^ 1][slot * 512]);
                int vrow = slot * 8 + srow;
                int vcg = scol ^ (vrow & 7);
                gload_lds16(Vbase + (size_t)vrow * S_SEQ + ktn + vcg * 8, &ldsV[pp ^ 1][slot * 512]);
            }
        }

        // S^T = K * Q^T : A = K-frag (rows=keys, 64), B = Q-frag (cols=q)
        floatx16 sa[2];
        #pragma unroll
        for (int jr = 0; jr < 2; ++jr)
            #pragma unroll
            for (int e = 0; e < 16; ++e) sa[jr][e] = 0.f;
        __builtin_amdgcn_s_setprio(1);
        #pragma unroll
        for (int ks = 0; ks < 8; ++ks) {
            #pragma unroll
            for (int jr = 0; jr < 2; ++jr) {
                int row = jr * 32 + c31;
                bf16x8 kf = *(const bf16x8*)&ldsK[pp][row * 128 + (((ks * 2 + h) ^ r7)) * 8];
                sa[jr] = __builtin_amdgcn_mfma_f32_32x32x16_bf16(kf, qf[ks], sa[jr], 0, 0, 0);
            }
        }
        __builtin_amdgcn_s_setprio(0);

        // causal mask: diagonal spans the last TWO 64-key tiles of this 128-q block
        if (kti >= nkt - 2) {
            #pragma unroll
            for (int jr = 0; jr < 2; ++jr)
                #pragma unroll
                for (int rr = 0; rr < 16; ++rr) {
                    int key = kt + jr * 32 + (rr & 3) + 8 * (rr >> 2) + 4 * h;
                    if (key > qcol) sa[jr][rr] = -1e30f;
                }
        }

        // online softmax over this lane's q column (one cross-half shuffle)
        float mx = -1e30f;
        #pragma unroll
        for (int jr = 0; jr < 2; ++jr)
            #pragma unroll
            for (int rr = 0; rr < 16; ++rr) mx = fmaxf(mx, sa[jr][rr]);
        mx = fmaxf(mx, __shfl_xor(mx, 32));

        // T13 defer-max: rescale only when the running max grew by > 8 (log2 units)
        if (!__all(mx - m_st <= 8.0f)) {
            float mn = fmaxf(m_st, mx);
            float al = __builtin_amdgcn_exp2f(m_st - mn);
            m_st = mn;
            l_st *= al;
            #pragma unroll
            for (int jd = 0; jd < 4; ++jd)
                #pragma unroll
                for (int e = 0; e < 16; ++e) oa[jd][e] *= al;
        }

        float rs = 0.f;
        bf16x8 pf[4];
        #pragma unroll
        for (int jr = 0; jr < 2; ++jr) {
            bf16x4 pk[4];
            #pragma unroll
            for (int g = 0; g < 4; ++g)
                #pragma unroll
                for (int e = 0; e < 4; ++e) {
                    float p = __builtin_amdgcn_exp2f(sa[jr][g * 4 + e] - m_st);
                    rs += p;
                    pk[g][e] = (bf16_t)p;
                }
            pf[jr * 2]     = make_pfrag(pk[0], pk[1], h);
            pf[jr * 2 + 1] = make_pfrag(pk[2], pk[3], h);
        }
        rs += __shfl_xor(rs, 32);
        l_st += rs;

        // O^T += V^T * P^T : A = V^T-frag (rows=d), B = P-frag (cols=q)
        __builtin_amdgcn_s_setprio(1);
        #pragma unroll
        for (int kb = 0; kb < 4; ++kb) {
            #pragma unroll
            for (int jd = 0; jd < 4; ++jd) {
                int row = jd * 32 + c31;
                bf16x8 vf = *(const bf16x8*)&ldsV[pp][row * 64 + (((kb * 2 + h) ^ r7)) * 8];
                oa[jd] = __builtin_amdgcn_mfma_f32_32x32x16_bf16(vf, pf[kb], oa[jd], 0, 0, 0);
            }
        }
        __builtin_amdgcn_s_setprio(0);
        pp ^= 1;
    }

    // epilogue: O^T C-layout: col q = qcol, row d = jd*32 + (r&3)+8*(r>>2)+4h
    float inv = 1.0f / l_st;
    bf16_t* op = O + ((size_t)b * S_SEQ + qcol) * S_HID + hd * S_HD;
    #pragma unroll
    for (int jd = 0; jd < 4; ++jd)
        #pragma unroll
        for (int g = 0; g < 4; ++g) {
            bf16x4 ov;
            #pragma unroll
            for (int e = 0; e < 4; ++e) ov[e] = (bf16_t)(oa[jd][g * 4 + e] * inv);
            *(bf16x4*)&op[jd * 32 + g * 8 + 4 * h] = ov;
        }
}

extern "C" void kernel_launch(void* const* d_in, const int* in_sizes, int n_in,
                              void* d_out, int out_size, void* d_ws, size_t ws_size,
                              hipStream_t stream) {
    const float* hs = (const float*)d_in[0];
    const float* qw = (const float*)d_in[1];
    const float* kw = (const float*)d_in[2];
    const float* vw = (const float*)d_in[3];
    const float* ow = (const float*)d_in[4];
    const float* qbias = (const float*)d_in[5];
    const float* kbias = (const float*)d_in[6];
    const float* vbias = (const float*)d_in[7];
    const float* obias = (const float*)d_in[8];

    char* ws = (char*)d_ws;
    bf16_t* Xb   = (bf16_t*)(ws + 0);           // 16 MB, reused as attention output
    bf16_t* Wqkv = (bf16_t*)(ws + 16777216);    // 32 MB stacked [q|k|v|o]
    bf16_t* Wob  = (bf16_t*)(ws + 41943040);    // last 8 MB of the stack
    bf16_t* Qb   = (bf16_t*)(ws + 50331648);    // 16 MB each
    bf16_t* Kb   = (bf16_t*)(ws + 67108864);
    bf16_t* Vtb  = (bf16_t*)(ws + 83886080);
    bf16_t* Ob   = Xb;                          // X dead after QKV GEMM

    cvt_all<<<2048, 256, 0, stream>>>(hs, qw, kw, vw, ow, Xb, Wqkv);

    // fold softmax scale 1/sqrt(128) and log2(e) into Q
    const float qscale = 0.08838834764831845f * 1.4426950408889634f;
    gemm_qkv<<<dim3(48, 32), 256, 0, stream>>>(Xb, Wqkv, qbias, kbias, vbias,
                                               Qb, Kb, Vtb, qscale);

    // 512 blocks: bh = bx&31, q-tile = (bx>>5)<8 ? idx : 23-idx
    attn<<<512, 256, 0, stream>>>(Qb, Kb, Vtb, Ob);

    gemm_out<<<dim3(16, 32), 256, 0, stream>>>(Ob, Wob, obias, (float*)d_out);
}

// Round 5
// 355.249 us; speedup vs baseline: 1.0474x; 1.0474x over previous
//
#include <hip/hip_runtime.h>

// Sizes are fixed by the problem.
#define S_HID 2048
#define S_SEQ 2048
#define S_B   2
#define S_NH  16
#define S_HD  128
#define S_M   (S_B * S_SEQ)   // 4096 rows
#define S_BH  (S_B * S_NH)    // 32

typedef __bf16 bf16_t;
typedef __bf16 bf16x8 __attribute__((ext_vector_type(8)));
typedef __bf16 bf16x4 __attribute__((ext_vector_type(4)));
typedef float  floatx4 __attribute__((ext_vector_type(4)));
typedef float  floatx16 __attribute__((ext_vector_type(16)));

typedef __attribute__((address_space(1))) unsigned int as1_uint;
typedef __attribute__((address_space(3))) unsigned int as3_uint;

// async global->LDS, 16B per lane; LDS dest = wave-uniform base + lane*16
__device__ __forceinline__ void gload_lds16(const void* g, void* l) {
    __builtin_amdgcn_global_load_lds((as1_uint*)g, (as3_uint*)l, 16, 0, 0);
}

// ---------------- fp32 -> bf16 convert: X + all 4 weights in one launch ----------------
__global__ void cvt_all(const float* __restrict__ x,
                        const float* __restrict__ qw, const float* __restrict__ kw,
                        const float* __restrict__ vw, const float* __restrict__ ow,
                        bf16_t* __restrict__ Xb, bf16_t* __restrict__ Wqkv) {
    const int XV = (S_M * S_HID) >> 2;      // 2^21 vec4
    const int WV = (S_HID * S_HID) >> 2;    // 2^20 vec4 per weight
    const int total = XV + 4 * WV;
    int stride = gridDim.x * blockDim.x;
    for (int i = blockIdx.x * blockDim.x + threadIdx.x; i < total; i += stride) {
        const float* src;
        bf16x4* dst;
        int local;
        if (i < XV) {
            src = x; local = i; dst = (bf16x4*)Xb;
        } else {
            int j = i - XV;
            int r = j >> 20;
            local = j & (WV - 1);
            src = r == 0 ? qw : r == 1 ? kw : r == 2 ? vw : ow;
            dst = (bf16x4*)Wqkv + (size_t)r * WV;
        }
        float4 v = ((const float4*)src)[local];
        bf16x4 o;
        o.x = (bf16_t)v.x; o.y = (bf16_t)v.y; o.z = (bf16_t)v.z; o.w = (bf16_t)v.w;
        dst[local] = o;
    }
}

// ---------------- fused QKV GEMM ----------------
// A[4096x2048] bf16, Wqkv stacked [6144x2048] bf16. Grid (48, 32).
// 128x128 tile, single-buffered 2-barrier structure. PINNED: measured optimum
// (~104 µs, ~990 TF, MfmaUtil 44%). Deep-pipeline rewrites regressed twice
// (R1 256^2 8-phase: 137 µs; R3 128x256 triple-buffer counted-vmcnt: 121 µs)
// — at 1 block/CU the counted-vmcnt schedule loses more TLP than it gains
// pipeline depth. Do not re-attempt without different geometry.
__global__ __launch_bounds__(256, 4)
void gemm_qkv(const bf16_t* __restrict__ A, const bf16_t* __restrict__ W,
              const float* __restrict__ qbias, const float* __restrict__ kbias,
              const float* __restrict__ vbias,
              bf16_t* __restrict__ Qo, bf16_t* __restrict__ Ko, bf16_t* __restrict__ Vto,
              float qscale) {
    __shared__ __align__(16) bf16_t ldsA[128 * 64];
    __shared__ __align__(16) bf16_t ldsB[128 * 64];
    const int tid = threadIdx.x;
    const int wid = tid >> 6, lane = tid & 63;
    const int m0 = blockIdx.y * 128, n0 = blockIdx.x * 128;
    const int wm = (wid & 1) * 64, wn = (wid >> 1) * 64;
    const int lm = lane & 15, quad = lane >> 4;
    const int srow = lane >> 3;
    const int scol = lane & 7;

    floatx4 acc[4][4];
    #pragma unroll
    for (int i = 0; i < 4; ++i)
        #pragma unroll
        for (int j = 0; j < 4; ++j)
            acc[i][j] = (floatx4){0.f, 0.f, 0.f, 0.f};

    for (int kt = 0; kt < S_HID; kt += 64) {
        #pragma unroll
        for (int i = 0; i < 4; ++i) {
            int slot = i * 4 + wid;
            int row = slot * 8 + srow;
            int cg = scol ^ (row & 7);
            gload_lds16(A + (size_t)(m0 + row) * S_HID + kt + cg * 8, &ldsA[slot * 512]);
            gload_lds16(W + (size_t)(n0 + row) * S_HID + kt + cg * 8, &ldsB[slot * 512]);
        }
        __syncthreads();
        #pragma unroll
        for (int k2 = 0; k2 < 2; ++k2) {
            bf16x8 af[4], bfr[4];
            #pragma unroll
            for (int i = 0; i < 4; ++i) {
                int row = wm + i * 16 + lm;
                int cc = (k2 * 4 + quad) ^ (row & 7);
                af[i] = *(const bf16x8*)&ldsA[row * 64 + cc * 8];
            }
            #pragma unroll
            for (int j = 0; j < 4; ++j) {
                int row = wn + j * 16 + lm;
                int cc = (k2 * 4 + quad) ^ (row & 7);
                bfr[j] = *(const bf16x8*)&ldsB[row * 64 + cc * 8];
            }
            #pragma unroll
            for (int i = 0; i < 4; ++i)
                #pragma unroll
                for (int j = 0; j < 4; ++j)
                    acc[i][j] = __builtin_amdgcn_mfma_f32_16x16x32_bf16(af[i], bfr[j], acc[i][j], 0, 0, 0);
        }
        __syncthreads();
    }

    const int region = n0 >> 11;   // 0=Q, 1=K, 2=V (wave-uniform)
    if (region < 2) {
        bf16_t* Ob = region ? Ko : Qo;
        const float* bias = region ? kbias : qbias;
        float scale = region ? 1.0f : qscale;
        #pragma unroll
        for (int i = 0; i < 4; ++i) {
            #pragma unroll
            for (int j = 0; j < 4; ++j) {
                int n = n0 + wn + j * 16 + lm;
                float bv = bias[n & 2047];
                int nl = n & 2047;
                int h = nl >> 7, d = nl & 127;
                #pragma unroll
                for (int r = 0; r < 4; ++r) {
                    int m = m0 + wm + i * 16 + quad * 4 + r;
                    int b = m >> 11, s = m & 2047;
                    Ob[(((size_t)(b * S_NH + h)) * S_SEQ + s) * S_HD + d] =
                        (bf16_t)((acc[i][j][r] + bv) * scale);
                }
            }
        }
    } else {
        // V^T: out[((b*16+h)*128 + d) * 2048 + s], 4 consecutive s per store
        #pragma unroll
        for (int i = 0; i < 4; ++i) {
            #pragma unroll
            for (int j = 0; j < 4; ++j) {
                int n = n0 + wn + j * 16 + lm;
                int nl = n & 2047;
                float bv = vbias[nl];
                int h = nl >> 7, d = nl & 127;
                int m = m0 + wm + i * 16 + quad * 4;
                int b = m >> 11, s = m & 2047;
                bf16x4 ov;
                #pragma unroll
                for (int r = 0; r < 4; ++r) ov[r] = (bf16_t)(acc[i][j][r] + bv);
                *(bf16x4*)&Vto[(((size_t)(b * S_NH + h)) * S_HD + d) * S_SEQ + s] = ov;
            }
        }
    }
}

// ---------------- output GEMM: out = A[4096x2048] * W[2048x2048]^T + bias (fp32) ----------------
__global__ __launch_bounds__(256, 3)
void gemm_out(const bf16_t* __restrict__ A, const bf16_t* __restrict__ W,
              const float* __restrict__ bias, float* __restrict__ out) {
    __shared__ __align__(16) bf16_t ldsA[128 * 64];
    __shared__ __align__(16) bf16_t ldsB[128 * 64];
    const int tid = threadIdx.x;
    const int wid = tid >> 6, lane = tid & 63;
    const int m0 = blockIdx.y * 128, n0 = blockIdx.x * 128;
    const int wm = (wid & 1) * 64, wn = (wid >> 1) * 64;
    const int lm = lane & 15, quad = lane >> 4;
    const int srow = lane >> 3;
    const int scol = lane & 7;

    floatx4 acc[4][4];
    #pragma unroll
    for (int i = 0; i < 4; ++i)
        #pragma unroll
        for (int j = 0; j < 4; ++j)
            acc[i][j] = (floatx4){0.f, 0.f, 0.f, 0.f};

    for (int kt = 0; kt < S_HID; kt += 64) {
        #pragma unroll
        for (int i = 0; i < 4; ++i) {
            int slot = i * 4 + wid;
            int row = slot * 8 + srow;
            int cg = scol ^ (row & 7);
            gload_lds16(A + (size_t)(m0 + row) * S_HID + kt + cg * 8, &ldsA[slot * 512]);
            gload_lds16(W + (size_t)(n0 + row) * S_HID + kt + cg * 8, &ldsB[slot * 512]);
        }
        __syncthreads();
        #pragma unroll
        for (int k2 = 0; k2 < 2; ++k2) {
            bf16x8 af[4], bfr[4];
            #pragma unroll
            for (int i = 0; i < 4; ++i) {
                int row = wm + i * 16 + lm;
                int cc = (k2 * 4 + quad) ^ (row & 7);
                af[i] = *(const bf16x8*)&ldsA[row * 64 + cc * 8];
            }
            #pragma unroll
            for (int j = 0; j < 4; ++j) {
                int row = wn + j * 16 + lm;
                int cc = (k2 * 4 + quad) ^ (row & 7);
                bfr[j] = *(const bf16x8*)&ldsB[row * 64 + cc * 8];
            }
            #pragma unroll
            for (int i = 0; i < 4; ++i)
                #pragma unroll
                for (int j = 0; j < 4; ++j)
                    acc[i][j] = __builtin_amdgcn_mfma_f32_16x16x32_bf16(af[i], bfr[j], acc[i][j], 0, 0, 0);
        }
        __syncthreads();
    }

    #pragma unroll
    for (int i = 0; i < 4; ++i) {
        #pragma unroll
        for (int j = 0; j < 4; ++j) {
            int n = n0 + wn + j * 16 + lm;
            float bv = bias[n];
            #pragma unroll
            for (int r = 0; r < 4; ++r) {
                int m = m0 + wm + i * 16 + quad * 4 + r;
                out[(size_t)m * S_HID + n] = acc[i][j][r] + bv;
            }
        }
    }
}

// Build PV B-fragment (16 keys) from packed P values via cross-half exchange.
__device__ __forceinline__ bf16x8 make_pfrag(bf16x4 lo, bf16x4 hi, int h) {
    int2 li = __builtin_bit_cast(int2, lo);
    int2 hh = __builtin_bit_cast(int2, hi);
    int2 xl, xh;
    xl.x = __shfl_xor(li.x, 32); xl.y = __shfl_xor(li.y, 32);
    xh.x = __shfl_xor(hh.x, 32); xh.y = __shfl_xor(hh.y, 32);
    int2 flo, fhi;
    flo.x = h ? xh.x : li.x;  flo.y = h ? xh.y : li.y;
    fhi.x = h ? hh.x : xl.x;  fhi.y = h ? hh.y : xl.y;
    bf16x4 a = __builtin_bit_cast(bf16x4, flo);
    bf16x4 b = __builtin_bit_cast(bf16x4, fhi);
    return __builtin_shufflevector(a, b, 0, 1, 2, 3, 4, 5, 6, 7);
}

// ---------------- flash attention (causal), S^T orientation, 64-key tiles ----------------
// Q,K: [bh][s][d] bf16 (Q pre-scaled by 1/sqrt(d)*log2e); Vt: [bh][d][s] bf16
// O: [b][s][h*128+d] bf16.
// Grid 512: bh = bx&31 (same-bh blocks share XCD), idx = bx>>5;
// qt = idx<8 ? idx : 23-idx  -> blocks bx and bx+256 (likely co-resident on a
// CU) have complementary work (36 half-tiles total). 64-key K/V tiles,
// double-buffered: LDS = 64KB -> 2 blocks/CU, 2 waves/SIMD co-scheduling.
// T5: setprio(1) around the MFMA clusters — waves here are phase-diverse
// (one barrier per tile, 2 independent blocks/CU), the regime where it pays
// (R2-vs-R0 paired totals: 360.7 vs 367.0). defer-max (T13) REVERTED: the
// only controlled A/B (R2-source 360.7 vs R4-source 372.1, identical qkv)
// scored it -11 µs here — the per-tile __all+branch doesn't pay on this
// 64-float rescale.
// NOTE: with 64-key tiles under a 128-q block the causal diagonal spans the
// LAST TWO key-tiles -> mask applies for kti >= nkt-2 (was the R5 bug).
__global__ __launch_bounds__(256, 2)
void attn(const bf16_t* __restrict__ Q, const bf16_t* __restrict__ K,
          const bf16_t* __restrict__ Vt, bf16_t* __restrict__ O) {
    __shared__ __align__(16) bf16_t ldsK[2][64 * 128];    // 2 x 16KB
    __shared__ __align__(16) bf16_t ldsV[2][128 * 64];    // 2 x 16KB
    const int tid = threadIdx.x, wid = tid >> 6, lane = tid & 63;
    const int lm = lane & 15, quad = lane >> 4;           // K staging roles
    const int srow = lane >> 3, scol = lane & 7;          // V staging roles
    const int c31 = lane & 31, h = lane >> 5, r7 = lane & 7;  // compute roles
    const int bx = blockIdx.x;
    const int bh = bx & 31, idx = bx >> 5;
    const int qt = idx < 8 ? idx : 23 - idx;
    const int q0 = qt * 128;
    const int b = bh >> 4, hd = bh & 15;

    const bf16_t* Kbase = K + (size_t)bh * S_SEQ * S_HD;
    const bf16_t* Vbase = Vt + (size_t)bh * S_HD * S_SEQ;

    const int qcol = q0 + wid * 32 + c31;      // this lane's q (= S^T column)
    const int nkt = qt * 2 + 2;                // 64-key tiles

    // Q fragments (B-operand): B[k = ks*16 + h*8 + j][n = c31]
    bf16x8 qf[8];
    {
        const bf16_t* qp = Q + ((size_t)bh * S_SEQ + qcol) * S_HD + h * 8;
        #pragma unroll
        for (int ks = 0; ks < 8; ++ks) qf[ks] = *(const bf16x8*)(qp + ks * 16);
    }

    floatx16 oa[4];
    #pragma unroll
    for (int jd = 0; jd < 4; ++jd)
        #pragma unroll
        for (int e = 0; e < 16; ++e) oa[jd][e] = 0.f;
    float m_st = -1e30f, l_st = 0.f;

    // stage tile 0 into buf 0
    #pragma unroll
    for (int i = 0; i < 4; ++i) {
        int slot = i * 4 + wid;                 // 0..15
        int krow = slot * 4 + quad;             // 0..63 (K: 4 rows x 256B per KB)
        int kcg = lm ^ (krow & 7);
        gload_lds16(Kbase + (size_t)krow * S_HD + kcg * 8, &ldsK[0][slot * 512]);
        int vrow = slot * 8 + srow;             // 0..127 (V: 8 rows x 128B per KB)
        int vcg = scol ^ (vrow & 7);
        gload_lds16(Vbase + (size_t)vrow * S_SEQ + vcg * 8, &ldsV[0][slot * 512]);
    }

    int pp = 0;
    for (int kti = 0; kti < nkt; ++kti) {
        const int kt = kti * 64;
        __syncthreads();   // drains staging of tile kti

        if (kti + 1 < nkt) {   // prefetch tile kti+1 into the other buffer
            const int ktn = kt + 64;
            #pragma unroll
            for (int i = 0; i < 4; ++i) {
                int slot = i * 4 + wid;
                int krow = slot * 4 + quad;
                int kcg = lm ^ (krow & 7);
                gload_lds16(Kbase + (size_t)(ktn + krow) * S_HD + kcg * 8, &ldsK[pp ^ 1][slot * 512]);
                int vrow = slot * 8 + srow;
                int vcg = scol ^ (vrow & 7);
                gload_lds16(Vbase + (size_t)vrow * S_SEQ + ktn + vcg * 8, &ldsV[pp ^ 1][slot * 512]);
            }
        }

        // S^T = K * Q^T : A = K-frag (rows=keys, 64), B = Q-frag (cols=q)
        floatx16 sa[2];
        #pragma unroll
        for (int jr = 0; jr < 2; ++jr)
            #pragma unroll
            for (int e = 0; e < 16; ++e) sa[jr][e] = 0.f;
        __builtin_amdgcn_s_setprio(1);
        #pragma unroll
        for (int ks = 0; ks < 8; ++ks) {
            #pragma unroll
            for (int jr = 0; jr < 2; ++jr) {
                int row = jr * 32 + c31;
                bf16x8 kf = *(const bf16x8*)&ldsK[pp][row * 128 + (((ks * 2 + h) ^ r7)) * 8];
                sa[jr] = __builtin_amdgcn_mfma_f32_32x32x16_bf16(kf, qf[ks], sa[jr], 0, 0, 0);
            }
        }
        __builtin_amdgcn_s_setprio(0);

        // causal mask: diagonal spans the last TWO 64-key tiles of this 128-q block
        if (kti >= nkt - 2) {
            #pragma unroll
            for (int jr = 0; jr < 2; ++jr)
                #pragma unroll
                for (int rr = 0; rr < 16; ++rr) {
                    int key = kt + jr * 32 + (rr & 3) + 8 * (rr >> 2) + 4 * h;
                    if (key > qcol) sa[jr][rr] = -1e30f;
                }
        }

        // online softmax over this lane's q column (one cross-half shuffle)
        float mx = -1e30f;
        #pragma unroll
        for (int jr = 0; jr < 2; ++jr)
            #pragma unroll
            for (int rr = 0; rr < 16; ++rr) mx = fmaxf(mx, sa[jr][rr]);
        mx = fmaxf(mx, __shfl_xor(mx, 32));
        float mn = fmaxf(m_st, mx);
        float al = __builtin_amdgcn_exp2f(m_st - mn);
        m_st = mn;

        float rs = 0.f;
        bf16x8 pf[4];
        #pragma unroll
        for (int jr = 0; jr < 2; ++jr) {
            bf16x4 pk[4];
            #pragma unroll
            for (int g = 0; g < 4; ++g)
                #pragma unroll
                for (int e = 0; e < 4; ++e) {
                    float p = __builtin_amdgcn_exp2f(sa[jr][g * 4 + e] - mn);
                    rs += p;
                    pk[g][e] = (bf16_t)p;
                }
            pf[jr * 2]     = make_pfrag(pk[0], pk[1], h);
            pf[jr * 2 + 1] = make_pfrag(pk[2], pk[3], h);
        }
        rs += __shfl_xor(rs, 32);
        l_st = l_st * al + rs;
        #pragma unroll
        for (int jd = 0; jd < 4; ++jd)
            #pragma unroll
            for (int e = 0; e < 16; ++e) oa[jd][e] *= al;

        // O^T += V^T * P^T : A = V^T-frag (rows=d), B = P-frag (cols=q)
        __builtin_amdgcn_s_setprio(1);
        #pragma unroll
        for (int kb = 0; kb < 4; ++kb) {
            #pragma unroll
            for (int jd = 0; jd < 4; ++jd) {
                int row = jd * 32 + c31;
                bf16x8 vf = *(const bf16x8*)&ldsV[pp][row * 64 + (((kb * 2 + h) ^ r7)) * 8];
                oa[jd] = __builtin_amdgcn_mfma_f32_32x32x16_bf16(vf, pf[kb], oa[jd], 0, 0, 0);
            }
        }
        __builtin_amdgcn_s_setprio(0);
        pp ^= 1;
    }

    // epilogue: O^T C-layout: col q = qcol, row d = jd*32 + (r&3)+8*(r>>2)+4h
    float inv = 1.0f / l_st;
    bf16_t* op = O + ((size_t)b * S_SEQ + qcol) * S_HID + hd * S_HD;
    #pragma unroll
    for (int jd = 0; jd < 4; ++jd)
        #pragma unroll
        for (int g = 0; g < 4; ++g) {
            bf16x4 ov;
            #pragma unroll
            for (int e = 0; e < 4; ++e) ov[e] = (bf16_t)(oa[jd][g * 4 + e] * inv);
            *(bf16x4*)&op[jd * 32 + g * 8 + 4 * h] = ov;
        }
}

extern "C" void kernel_launch(void* const* d_in, const int* in_sizes, int n_in,
                              void* d_out, int out_size, void* d_ws, size_t ws_size,
                              hipStream_t stream) {
    const float* hs = (const float*)d_in[0];
    const float* qw = (const float*)d_in[1];
    const float* kw = (const float*)d_in[2];
    const float* vw = (const float*)d_in[3];
    const float* ow = (const float*)d_in[4];
    const float* qbias = (const float*)d_in[5];
    const float* kbias = (const float*)d_in[6];
    const float* vbias = (const float*)d_in[7];
    const float* obias = (const float*)d_in[8];

    char* ws = (char*)d_ws;
    bf16_t* Xb   = (bf16_t*)(ws + 0);           // 16 MB, reused as attention output
    bf16_t* Wqkv = (bf16_t*)(ws + 16777216);    // 32 MB stacked [q|k|v|o]
    bf16_t* Wob  = (bf16_t*)(ws + 41943040);    // last 8 MB of the stack
    bf16_t* Qb   = (bf16_t*)(ws + 50331648);    // 16 MB each
    bf16_t* Kb   = (bf16_t*)(ws + 67108864);
    bf16_t* Vtb  = (bf16_t*)(ws + 83886080);
    bf16_t* Ob   = Xb;                          // X dead after QKV GEMM

    cvt_all<<<2048, 256, 0, stream>>>(hs, qw, kw, vw, ow, Xb, Wqkv);

    // fold softmax scale 1/sqrt(128) and log2(e) into Q
    const float qscale = 0.08838834764831845f * 1.4426950408889634f;
    gemm_qkv<<<dim3(48, 32), 256, 0, stream>>>(Xb, Wqkv, qbias, kbias, vbias,
                                               Qb, Kb, Vtb, qscale);

    // 512 blocks: bh = bx&31, q-tile = (bx>>5)<8 ? idx : 23-idx
    attn<<<512, 256, 0, stream>>>(Qb, Kb, Vtb, Ob);

    gemm_out<<<dim3(16, 32), 256, 0, stream>>>(Ob, Wob, obias, (float*)d_out);
}